// Round 7
// baseline (551.321 us; speedup 1.0000x reference)
//
#include <hip/hip_runtime.h>

typedef unsigned short u16;
typedef __attribute__((ext_vector_type(8))) short short8;
typedef __attribute__((ext_vector_type(4))) short short4v;
typedef __attribute__((ext_vector_type(4))) float f32x4;
typedef __attribute__((ext_vector_type(4))) unsigned short u16x4;

static constexpr int TB   = 2;
static constexpr int TT   = 2048;
static constexpr int TD   = 1024;
static constexpr int TNH  = 16;
static constexpr int TDH  = 64;
static constexpr int TFFN = 2736;
static constexpr int TFFNP= 2752;   // K padded to multiple of 32
static constexpr int TBT  = TB * TT;

#define DEVI static __device__ __forceinline__

typedef __attribute__((address_space(1))) const unsigned int gas_t;
typedef __attribute__((address_space(3))) unsigned int las_t;
#define GLOAD16(src, dst) __builtin_amdgcn_global_load_lds((gas_t*)(src), (las_t*)(dst), 16, 0, 0)

DEVI u16 f2bf(float f) {
  union { float f; unsigned u; } v; v.f = f;
  unsigned r = v.u + 0x7FFFu + ((v.u >> 16) & 1u);
  return (u16)(r >> 16);
}
DEVI float bf2f(u16 u) {
  union { unsigned u; float f; } v; v.u = ((unsigned)u) << 16;
  return v.f;
}

// packed f32x2 -> bf16x2 (RNE), gfx950 v_cvt_pk_bf16_f32
DEVI unsigned cvtpk(float lo, float hi) {
  unsigned r;
  asm("v_cvt_pk_bf16_f32 %0, %1, %2" : "=v"(r) : "v"(lo), "v"(hi));
  return r;
}

#if __has_builtin(__builtin_amdgcn_mfma_f32_16x16x16bf16_1k)
#define MFMA16(a, b, c) __builtin_amdgcn_mfma_f32_16x16x16bf16_1k(a, b, c, 0, 0, 0)
#else
DEVI f32x4 mfma16_asm(short4v a, short4v b, f32x4 c) {
  asm("v_mfma_f32_16x16x16_bf16 %0, %1, %2, %0" : "+v"(c) : "v"(a), "v"(b));
  return c;
}
#define MFMA16(a, b, c) mfma16_asm(a, b, c)
#endif

// ------------------- merged converts (single launch) -----------------------
__global__ void k_cvt_all(const float* __restrict__ x,  const float* __restrict__ lw,
                          const float* __restrict__ wq, const float* __restrict__ wo,
                          const float* __restrict__ gw, const float* __restrict__ uw,
                          const float* __restrict__ dw, const float* __restrict__ ddw,
                          u16* __restrict__ xb,  u16* __restrict__ wbl,
                          u16* __restrict__ wbq, u16* __restrict__ wbo,
                          u16* __restrict__ wbgu, u16* __restrict__ wbd,
                          u16* __restrict__ wcat) {
  constexpr int U0 = TBT * TD / 4;        // x -> xb
  constexpr int U1 = TD * TD / 4;         // lerp_w
  constexpr int U2 = 3 * TD * TD / 4;     // w_qkv
  constexpr int U3 = TD * TD / 4;         // w_o
  constexpr int U4 = TFFN * TD / 4;       // gate
  constexpr int U5 = TFFN * TD / 4;       // up
  constexpr int U6 = TD * (TFFNP / 4);    // down (pad 2736->2752)
  constexpr int U7 = 256 * TD / 4;        // dd_w split3
  constexpr int P1 = U0, P2 = P1 + U1, P3 = P2 + U2, P4 = P3 + U3;
  constexpr int P5 = P4 + U4, P6 = P5 + U5, P7 = P6 + U6, PT = P7 + U7;
  int i = blockIdx.x * blockDim.x + threadIdx.x;
  int st = gridDim.x * blockDim.x;
  for (; i < PT; i += st) {
    if (i < P6) {
      const float* s; u16* d; int j;
      if (i < P1)      { s = x;  d = xb;  j = i; }
      else if (i < P2) { s = lw; d = wbl; j = i - P1; }
      else if (i < P3) { s = wq; d = wbq; j = i - P2; }
      else if (i < P4) { s = wo; d = wbo; j = i - P3; }
      else if (i < P5) { s = gw; d = wbgu; j = i - P4; }
      else             { s = uw; d = wbgu + (size_t)TFFN * TD; j = i - P5; }
      float4 v = ((const float4*)s)[j];
      u16x4 u;
      u.x = f2bf(v.x); u.y = f2bf(v.y); u.z = f2bf(v.z); u.w = f2bf(v.w);
      ((u16x4*)d)[j] = u;
    } else if (i < P7) {
      int j = i - P6;
      int c4 = j % (TFFNP / 4), r = j / (TFFNP / 4);
      u16x4 u;
      if (c4 < TFFN / 4) {
        const float* sp = dw + (size_t)r * TFFN + c4 * 4;
        u.x = f2bf(sp[0]); u.y = f2bf(sp[1]); u.z = f2bf(sp[2]); u.w = f2bf(sp[3]);
      } else { u.x = u.y = u.z = u.w = 0; }
      ((u16x4*)wbd)[(size_t)r * (TFFNP / 4) + c4] = u;
    } else {
      int j = i - P7;                       // 4 src elems of dd_w [256][1024]
      int c = (j & 255) * 4, r = j >> 8;
      float4 v = *(const float4*)(ddw + (size_t)r * 1024 + c);
      size_t base = (size_t)r * 3072 + c;
      #pragma unroll
      for (int e = 0; e < 4; e++) {
        float f = (e == 0) ? v.x : (e == 1) ? v.y : (e == 2) ? v.z : v.w;
        u16 h = f2bf(f);
        wcat[base + e] = h;
        wcat[base + 1024 + e] = h;
        wcat[base + 2048 + e] = f2bf(f - bf2f(h));
      }
    }
  }
}

// ----------------------------- rmsnorm ------------------------------------
__global__ __launch_bounds__(256) void k_rmsnorm(const float* __restrict__ x,
                                                 const float* __restrict__ w,
                                                 u16* __restrict__ o) {
  int row = blockIdx.x;
  float4 v = ((const float4*)(x + (size_t)row * TD))[threadIdx.x];
  float ss = v.x*v.x + v.y*v.y + v.z*v.z + v.w*v.w;
  #pragma unroll
  for (int m = 1; m < 64; m <<= 1) ss += __shfl_xor(ss, m);
  __shared__ float red[4];
  if ((threadIdx.x & 63) == 0) red[threadIdx.x >> 6] = ss;
  __syncthreads();
  float tot = red[0] + red[1] + red[2] + red[3];
  float sc = rsqrtf(tot * (1.0f / TD) + 1e-6f);
  float4 wv = ((const float4*)w)[threadIdx.x];
  u16x4 u;
  u.x = f2bf(v.x * sc * wv.x); u.y = f2bf(v.y * sc * wv.y);
  u.z = f2bf(v.z * sc * wv.z); u.w = f2bf(v.w * sc * wv.w);
  ((u16x4*)(o + (size_t)row * TD))[threadIdx.x] = u;
}

enum { EPI_LERP = 0, EPI_DD = 1, EPI_RESID = 2, EPI_B16 = 3 };

// -------- triple-buffered pipelined GEMM (3 blocks/CU, race-free) ----------
// C[M][N] = A[M][K]*B[N][K]^T. BMx128 tile, BK=32, 4 waves, wave (BM/2)x64.
// THREE LDS K-step buffers (48KB @BM=128 -> 3 blocks/CU = 12 waves/CU).
// Per step: counted vmcnt (own stage(t) landed) BEFORE barrier => all waves'
// stage(t) landed at barrier => compute(t) race-free with no post-barrier
// wait; stages t+1/t+2 stay in flight across the barrier (T4).
// stage(t+2) post-barrier overwrites buf read at compute(t-1) => WAR-safe.
// LDS [row][32], 16B-unit ^= (row>>1)&3 on both source and read (Rule 21).
template<int BM, int EPI>
__global__ __launch_bounds__(256) void k_gemm_p4(
    const u16* __restrict__ A, const u16* __restrict__ B,
    int M, int N, int K,
    const float* __restrict__ aux0, const float* __restrict__ aux1,
    float* __restrict__ outF, u16* __restrict__ outB) {
  constexpr int MI = BM / 32;          // acc rows per wave
  alignas(16) __shared__ u16 As[3][BM * 32];
  alignas(16) __shared__ u16 Bs[3][4096];
  const int lane = threadIdx.x & 63;
  const int w  = threadIdx.x >> 6;
  const int ln = lane & 15;
  const int g  = lane >> 4;
  const int swz = (ln >> 1) & 3;
  const int m0 = blockIdx.x * BM;
  const int n0 = blockIdx.y * 128;
  const int wm = (w >> 1) * (BM / 2);
  const int wn = (w & 1) * 64;

  const f32x4 fz = {0.f, 0.f, 0.f, 0.f};
  f32x4 acc[MI][4];
  #pragma unroll
  for (int mi = 0; mi < MI; mi++)
    #pragma unroll
    for (int ni = 0; ni < 4; ni++) acc[mi][ni] = fz;

  const int rsub = lane >> 2;                       // row within 16-row unit
  const int csrc = (lane & 3) ^ ((lane >> 3) & 3);  // pre-swizzled k-unit
  auto stage = [&](int buf, int kt) {
    const int k0 = kt * 32 + csrc * 8;
    if constexpr (BM == 128) {
      #pragma unroll
      for (int i = 0; i < 2; i++) {
        const int u = w + i * 4;
        int ar = m0 + u * 16 + rsub;
        GLOAD16(A + (size_t)ar * K + k0, &As[buf][u * 512]);
        int br = n0 + u * 16 + rsub; if (br > N - 1) br = N - 1;
        GLOAD16(B + (size_t)br * K + k0, &Bs[buf][u * 512]);
      }
    } else {                     // BM == 64
      int ar = m0 + w * 16 + rsub;
      GLOAD16(A + (size_t)ar * K + k0, &As[buf][w * 512]);
      #pragma unroll
      for (int i = 0; i < 2; i++) {
        const int u = w + i * 4;
        int br = n0 + u * 16 + rsub; if (br > N - 1) br = N - 1;
        GLOAD16(B + (size_t)br * K + k0, &Bs[buf][u * 512]);
      }
    }
  };

  auto compute = [&](int cur) {
    short8 af[MI], bfr[4];
    #pragma unroll
    for (int mi = 0; mi < MI; mi++)
      af[mi] = *(const short8*)&As[cur][(wm + mi * 16 + ln) * 32 + ((g ^ swz) << 3)];
    #pragma unroll
    for (int ni = 0; ni < 4; ni++)
      bfr[ni] = *(const short8*)&Bs[cur][(wn + ni * 16 + ln) * 32 + ((g ^ swz) << 3)];
    __builtin_amdgcn_s_setprio(1);
    #pragma unroll
    for (int mi = 0; mi < MI; mi++)
      #pragma unroll
      for (int ni = 0; ni < 4; ni++)
        acc[mi][ni] = __builtin_amdgcn_mfma_f32_16x16x32_bf16(af[mi], bfr[ni], acc[mi][ni], 0, 0, 0);
    __builtin_amdgcn_s_setprio(0);
  };

  const int nt = K / 32;
  stage(0, 0);
  stage(1, 1);
  int cur = 0, nx2 = 2;                 // t%3, (t+2)%3
  for (int t = 0; t < nt; ++t) {
    if (t + 1 < nt) {
      if constexpr (BM == 128) asm volatile("s_waitcnt vmcnt(4)" ::: "memory");
      else                     asm volatile("s_waitcnt vmcnt(3)" ::: "memory");
    } else {
      asm volatile("s_waitcnt vmcnt(0)" ::: "memory");
    }
    __builtin_amdgcn_s_barrier();
    asm volatile("" ::: "memory");
    if (t + 2 < nt) stage(nx2, t + 2);
    compute(cur);
    cur = (cur == 2) ? 0 : cur + 1;
    nx2 = (nx2 == 2) ? 0 : nx2 + 1;
  }

  // epilogue: C layout col=lane&15, row=(lane>>4)*4+reg
  #pragma unroll
  for (int mi = 0; mi < MI; mi++) {
    #pragma unroll
    for (int ni = 0; ni < 4; ni++) {
      int col = n0 + wn + ni * 16 + ln;
      #pragma unroll
      for (int r = 0; r < 4; r++) {
        int row = m0 + wm + mi * 16 + g * 4 + r;
        if (row >= M || col >= N) continue;
        float c = acc[mi][ni][r];
        size_t o = (size_t)row * N + col;
        if constexpr (EPI == EPI_LERP) {
          float gg = 1.0f / (1.0f + __expf(-(c + aux1[col])));
          float xv = aux0[o];
          float xp = (row & (TT - 1)) ? aux0[o - N] : 0.0f;
          float res = xv + gg * (xp - xv);
          outF[o] = res;
          u16 hi = f2bf(res);
          size_t xc = (size_t)row * 3072 + col;
          outB[xc] = hi;
          outB[xc + 2048] = hi;
          outB[xc + 1024] = f2bf(res - bf2f(hi));
        } else if constexpr (EPI == EPI_DD) {
          outF[o] = c + aux1[col];
        } else if constexpr (EPI == EPI_RESID) {
          outF[o] = aux0[o] + c;
        } else {
          outB[o] = f2bf(c);
        }
      }
    }
  }
}

// ------------------------- cumsum (3-phase) --------------------------------
__global__ __launch_bounds__(64) void k_csum1(const float* __restrict__ ang,
                                              float* __restrict__ seg) {
  int b = blockIdx.x, sg = blockIdx.y, q = threadIdx.x;
  const float4* p = (const float4*)(ang + ((size_t)(b * TT + sg * 16)) * 256) + q;
  float4 a = {0.f, 0.f, 0.f, 0.f};
  #pragma unroll 4
  for (int i = 0; i < 16; i++) {
    float4 v = p[(size_t)i * 64];
    a.x += v.x; a.y += v.y; a.z += v.z; a.w += v.w;
  }
  ((float4*)(seg + ((size_t)(b * 128 + sg)) * 256))[q] = a;
}

// batched: 16 independent loads per round, then sequential prefix writeback
__global__ __launch_bounds__(512) void k_csum2(float* __restrict__ seg) {
  int b = threadIdx.x >> 8, col = threadIdx.x & 255;
  float run = 0.f;
  for (int s0 = 0; s0 < 128; s0 += 16) {
    float v[16];
    #pragma unroll
    for (int i = 0; i < 16; i++)
      v[i] = seg[((size_t)(b * 128 + s0 + i)) * 256 + col];
    #pragma unroll
    for (int i = 0; i < 16; i++) {
      float t = v[i];
      seg[((size_t)(b * 128 + s0 + i)) * 256 + col] = run;
      run += t;
    }
  }
}

__global__ __launch_bounds__(64) void k_csum3(const float* __restrict__ ang,
                                              const float* __restrict__ seg,
                                              float* __restrict__ dc,
                                              float* __restrict__ ds) {
  int b = blockIdx.x, sg = blockIdx.y, q = threadIdx.x;
  size_t rowbase = ((size_t)(b * TT + sg * 16)) * 256;
  const float4* p = (const float4*)(ang + rowbase) + q;
  float4 a = ((const float4*)(seg + ((size_t)(b * 128 + sg)) * 256))[q];
  for (int i = 0; i < 16; i++) {
    float4 v = p[(size_t)i * 64];
    a.x += v.x; a.y += v.y; a.z += v.z; a.w += v.w;
    float4 c, s;
    c.x = cosf(a.x); s.x = sinf(a.x);
    c.y = cosf(a.y); s.y = sinf(a.y);
    c.z = cosf(a.z); s.z = sinf(a.z);
    c.w = cosf(a.w); s.w = sinf(a.w);
    ((float4*)(dc + rowbase))[(size_t)i * 64 + q] = c;
    ((float4*)(ds + rowbase))[(size_t)i * 64 + q] = s;
  }
}

// ----------------- qkv post: head RMS + hybrid rope + V^T ------------------
__global__ __launch_bounds__(256) void k_qkv_post(
    const u16* __restrict__ qkv, const float* __restrict__ rc, const float* __restrict__ rs,
    const float* __restrict__ ddc, const float* __restrict__ dds,
    const float* __restrict__ qnw, const float* __restrict__ knw,
    const float* __restrict__ qpb, const float* __restrict__ kpb,
    u16* __restrict__ qb, u16* __restrict__ kb, u16* __restrict__ vT) {
  __shared__ u16 vt[64][72];
  const int lane = threadIdx.x & 63;
  const int w = threadIdx.x >> 6;
  const int bh = blockIdx.x, b = bh >> 4, h = bh & 15;
  const int t0 = blockIdx.y * 64;
  const float qsc = 0.125f * 1.44269504f;   // 1/sqrt(DH) * log2e
  const float qw = qnw[lane] * qpb[lane];
  const float kw = knw[lane] * kpb[lane];
  const float sgn = (lane & 16) ? 1.0f : -1.0f;
  #pragma unroll 4
  for (int it = 0; it < 16; ++it) {
    int tl = w * 16 + it;
    int t = t0 + tl;
    size_t base = ((size_t)(b * TT + t)) * 3072 + h * 64 + lane;
    float q = bf2f(qkv[base]);
    float k = bf2f(qkv[base + 1024]);
    float v = bf2f(qkv[base + 2048]);
    float sq = q * q, sk = k * k;
    #pragma unroll
    for (int m = 1; m < 64; m <<= 1) { sq += __shfl_xor(sq, m); sk += __shfl_xor(sk, m); }
    q *= rsqrtf(sq * (1.0f / TDH) + 1e-6f) * qw;
    k *= rsqrtf(sk * (1.0f / TDH) + 1e-6f) * kw;
    float c, s;
    if (lane < 32) {
      c = rc[t * 32 + (lane & 15)];
      s = rs[t * 32 + (lane & 15)];
    } else {
      size_t ti = ((size_t)(b * TT + t)) * 256 + h * 16 + (lane & 15);
      c = ddc[ti];
      s = dds[ti];
    }
    float oq = __shfl_xor(q, 16);
    float ok = __shfl_xor(k, 16);
    float qr = (q * c + sgn * oq * s) * qsc;
    float kr = k * c + sgn * ok * s;
    size_t o = ((size_t)(bh * TT + t)) * 64 + lane;
    qb[o] = f2bf(qr);
    kb[o] = f2bf(kr);
    vt[lane][tl] = f2bf(v);
  }
  __syncthreads();
  int row = threadIdx.x >> 2, sg = threadIdx.x & 3;
  short8 v0 = *(const short8*)&vt[row][sg * 16];
  short8 v1 = *(const short8*)&vt[row][sg * 16 + 8];
  size_t o = ((size_t)(bh * 64 + row)) * TT + t0 + sg * 16;
  *(short8*)(vT + o) = v0;
  *(short8*)(vT + o + 8) = v1;
}

// --------------------------- flash attention -------------------------------
__global__ __launch_bounds__(256) void k_attn(
    const u16* __restrict__ qb, const u16* __restrict__ kb,
    const u16* __restrict__ vT, u16* __restrict__ y) {
  __shared__ u16 smem[16384];         // Ks[2][4096] | Vs[2][4096]
  u16* Ks = smem;
  u16* Vs = smem + 8192;
  const int lane = threadIdx.x & 63;
  const int w = threadIdx.x >> 6;
  const int ln = lane & 15;
  const int g = lane >> 4;
  const int gh = g >> 1, gl = g & 1;
  const int bh = blockIdx.x;
  const int b = bh >> 4;
  const int by = 31 - (int)blockIdx.y;     // LPT: longest first
  const int qt0 = by * 64 + w * 16;
  const u16* Q  = qb + (size_t)bh * TT * TDH;
  const u16* Kp = kb + (size_t)bh * TT * TDH;
  const u16* Vp = vT + (size_t)bh * TDH * TT;
  short8 qa0 = *(const short8*)(Q + (size_t)(qt0 + ln) * TDH + g * 8);
  short8 qa1 = *(const short8*)(Q + (size_t)(qt0 + ln) * TDH + 32 + g * 8);
  const f32x4 fz = {0.f, 0.f, 0.f, 0.f};
  f32x4 O[4];
  #pragma unroll
  for (int r = 0; r < 4; r++) O[r] = fz;
  float m = -1e30f, l = 0.0f;
  const int qlim = qt0 + ln;

  auto stage = [&](int buf, int j0) {
    #pragma unroll
    for (int i = 0; i < 2; i++) {
      int r = w * 16 + i * 8 + (lane >> 3);
      int c = (lane & 7) ^ (r & 7);
      GLOAD16(Kp + (size_t)(j0 + r) * TDH + c * 8, &Ks[buf * 4096 + w * 1024 + i * 512]);
      GLOAD16(Vp + (size_t)r * TT + j0 + c * 8, &Vs[buf * 4096 + w * 1024 + i * 512]);
    }
  };

  const int nt = by + 1;
  stage(0, 0);
  __syncthreads();
  for (int jt = 0; jt < nt; ++jt) {
    const int cur = jt & 1;
    if (jt + 1 < nt) stage(cur ^ 1, (jt + 1) * 64);
    const int j0 = jt * 64;
    f32x4 sc[4];
    __builtin_amdgcn_s_setprio(1);
    #pragma unroll
    for (int c4 = 0; c4 < 4; c4++) {
      const u16* kr = Ks + cur * 4096 + (c4 * 16 + ln) * 64;
      short8 k0 = *(const short8*)(kr + ((g ^ (ln & 7)) * 8));
      short8 k1 = *(const short8*)(kr + (((g + 4) ^ (ln & 7)) * 8));
      f32x4 z = fz;
      z = __builtin_amdgcn_mfma_f32_16x16x32_bf16(k0, qa0, z, 0, 0, 0);
      z = __builtin_amdgcn_mfma_f32_16x16x32_bf16(k1, qa1, z, 0, 0, 0);
      sc[c4] = z;
    }
    __builtin_amdgcn_s_setprio(0);
    if (jt == nt - 1) {              // diagonal: mask j > q
      #pragma unroll
      for (int c4 = 0; c4 < 4; c4++)
        #pragma unroll
        for (int r = 0; r < 4; r++)
          if (j0 + c4 * 16 + g * 4 + r > qlim) sc[c4][r] = -1e30f;
    }
    float pm = sc[0][0];
    #pragma unroll
    for (int c4 = 0; c4 < 4; c4++)
      #pragma unroll
      for (int r = 0; r < 4; r++) pm = fmaxf(pm, sc[c4][r]);
    pm = fmaxf(pm, __shfl_xor(pm, 16));
    pm = fmaxf(pm, __shfl_xor(pm, 32));
    bool grow = pm > m + 10.0f;
    if (__ballot(grow) != 0ull) {
      float mn = fmaxf(m, pm);
      float corr = exp2f(m - mn);
      #pragma unroll
      for (int dc = 0; dc < 4; dc++)
        #pragma unroll
        for (int r = 0; r < 4; r++) O[dc][r] *= corr;
      l *= corr;
      m = mn;
    }
    float rs_ = 0.0f;
    #pragma unroll
    for (int c4 = 0; c4 < 4; c4++)
      #pragma unroll
      for (int r = 0; r < 4; r++) {
        float pv = exp2f(sc[c4][r] - m);
        rs_ += pv;
        sc[c4][r] = pv;
      }
    rs_ += __shfl_xor(rs_, 16);
    rs_ += __shfl_xor(rs_, 32);
    l += rs_;
    short4v p4[4];
    #pragma unroll
    for (int c4 = 0; c4 < 4; c4++) {
      union { unsigned u[2]; short4v s; } pu;
      pu.u[0] = cvtpk(sc[c4][0], sc[c4][1]);
      pu.u[1] = cvtpk(sc[c4][2], sc[c4][3]);
      p4[c4] = pu.s;
    }
    __builtin_amdgcn_s_setprio(1);
    #pragma unroll
    for (int dc = 0; dc < 4; dc++) {
      const int vrow = dc * 16 + ln;
      const u16* vbase = Vs + cur * 4096 + vrow * 64;
      #pragma unroll
      for (int c4 = 0; c4 < 4; c4++) {
        int chunk = (2 * c4 + gh) ^ (ln & 7);
        short4v va = *(const short4v*)(vbase + chunk * 8 + gl * 4);
        O[dc] = MFMA16(va, p4[c4], O[dc]);
      }
    }
    __builtin_amdgcn_s_setprio(0);
    __syncthreads();
  }
  // epilogue: transpose O^T via LDS for coalesced y writes
  u16* ot = smem + w * 1152;           // 16 rows x 72
  float inv = 1.0f / l;
  #pragma unroll
  for (int dc = 0; dc < 4; dc++)
    #pragma unroll
    for (int r = 0; r < 4; r += 2) {
      unsigned pk = cvtpk(O[dc][r] * inv, O[dc][r + 1] * inv);
      *(unsigned*)(ot + ln * 72 + dc * 16 + g * 4 + r) = pk;
    }
  __syncthreads();
  int row = (threadIdx.x & 63) >> 2, sg = threadIdx.x & 3;
  u16* os = smem + w * 1152;
  short8 v0 = *(const short8*)(os + row * 72 + sg * 16);
  short8 v1 = *(const short8*)(os + row * 72 + sg * 16 + 8);
  size_t o = ((size_t)(b * TT + qt0 + row)) * TD + (bh & 15) * TDH + sg * 16;
  *(short8*)(y + o) = v0;
  *(short8*)(y + o + 8) = v1;
}

// ------------------------------ swiglu -------------------------------------
__global__ void k_swiglu(const u16* __restrict__ gu, u16* __restrict__ hb) {
  int i = blockIdx.x * blockDim.x + threadIdx.x;
  int n = TBT * 344;
  if (i >= n) return;
  int c8 = i % 344, r = i / 344;
  short8 o;
  if (c8 < 342) {
    short8 gv = *(const short8*)(gu + (size_t)r * 5472 + c8 * 8);
    short8 uv = *(const short8*)(gu + (size_t)r * 5472 + 2736 + c8 * 8);
    #pragma unroll
    for (int j = 0; j < 8; j++) {
      float gf = bf2f((u16)gv[j]);
      float uf = bf2f((u16)uv[j]);
      float sg = gf / (1.0f + __expf(-gf));
      o[j] = (short)f2bf(sg * uf);
    }
  } else {
    #pragma unroll
    for (int j = 0; j < 8; j++) o[j] = 0;
  }
  *(short8*)(hb + (size_t)r * TFFNP + c8 * 8) = o;
}

// ----------------------------- launcher ------------------------------------
extern "C" void kernel_launch(void* const* d_in, const int* in_sizes, int n_in,
                              void* d_out, int out_size, void* d_ws, size_t ws_size,
                              hipStream_t stream) {
  const float* x      = (const float*)d_in[0];
  const float* ropec  = (const float*)d_in[1];
  const float* ropes  = (const float*)d_in[2];
  const float* lerp_w = (const float*)d_in[3];
  const float* lerp_b = (const float*)d_in[4];
  const float* anw    = (const float*)d_in[5];
  const float* w_qkv  = (const float*)d_in[6];
  const float* qnw    = (const float*)d_in[7];
  const float* knw    = (const float*)d_in[8];
  const float* qpb    = (const float*)d_in[9];
  const float* kpb    = (const float*)d_in[10];
  const float* dd_w   = (const float*)d_in[11];
  const float* dd_b   = (const float*)d_in[12];
  const float* w_o    = (const float*)d_in[13];
  const float* mnw    = (const float*)d_in[14];
  const float* gate_w = (const float*)d_in[15];
  const float* up_w   = (const float*)d_in[16];
  const float* down_w = (const float*)d_in[17];
  float* out = (float*)d_out;
  (void)in_sizes; (void)n_in; (void)out_size; (void)ws_size;

  char* ws = (char*)d_ws;
  size_t off = 0;
  auto alloc = [&](size_t bytes) -> char* {
    char* p = ws + off;
    off += (bytes + 255) & ~(size_t)255;
    return p;
  };

  // region A..E (dead before gate/up): aliased by gu_b (44.83MB <= 50.34MB)
  char* segA = ws;
  u16* xb      = (u16*)alloc((size_t)TBT * TD * 2);        // 8.39
  u16* wb_lerp = (u16*)alloc((size_t)TD * TD * 2);         // 2.10
  u16* wb_qkv  = (u16*)alloc((size_t)3 * TD * TD * 2);     // 6.29
  u16* h_b     = (u16*)alloc((size_t)TBT * TD * 2);        // 8.39
  u16* xcat    = (u16*)alloc((size_t)TBT * 3072 * 2);      // 25.17
  u16* gu_b    = (u16*)segA;

  // region F (dead before swiglu): aliased by hb (22.53 <= 25.17)
  char* segF = ws + off;
  u16* qkv_b   = (u16*)alloc((size_t)TBT * 3 * TD * 2);    // 25.17
  u16* hb      = (u16*)segF;

  // persistent
  u16* wcat    = (u16*)alloc((size_t)256 * 3072 * 2);
  u16* wb_o    = (u16*)alloc((size_t)TD * TD * 2);
  u16* wb_gu   = (u16*)alloc((size_t)2 * TFFN * TD * 2);
  u16* wb_down = (u16*)alloc((size_t)TD * TFFNP * 2);
  float* x_mix = (float*)alloc((size_t)TBT * TD * 4);
  float* angles= (float*)alloc((size_t)TBT * 256 * 4);
  float* ddc   = (float*)alloc((size_t)TBT * 256 * 4);
  float* dds   = (float*)alloc((size_t)TBT * 256 * 4);
  float* segsum= (float*)alloc((size_t)2 * 128 * 256 * 4);
  u16* qb  = (u16*)alloc((size_t)TBT * TD * 2);
  u16* kb  = (u16*)alloc((size_t)TBT * TD * 2);
  u16* vT  = (u16*)alloc((size_t)TBT * TD * 2);
  u16* y_b = (u16*)alloc((size_t)TBT * TD * 2);
  float* x2  = (float*)alloc((size_t)TBT * TD * 4);
  u16* h2_b  = (u16*)alloc((size_t)TBT * TD * 2);

  // --- all dtype converts in one launch ---
  k_cvt_all<<<dim3(2048), dim3(256), 0, stream>>>(
      x, lerp_w, w_qkv, w_o, gate_w, up_w, down_w, dd_w,
      xb, wb_lerp, wb_qkv, wb_o, wb_gu, wb_down, wcat);

  // --- lerp gate (x = (1-g)x + g x_prev), also emits xcat = [hi|lo|hi] ---
  k_gemm_p4<128, EPI_LERP><<<dim3(32, 8), dim3(256), 0, stream>>>(
      xb, wb_lerp, TBT, TD, TD, x, lerp_b, x_mix, xcat);

  k_rmsnorm<<<dim3(TBT), dim3(256), 0, stream>>>(x_mix, anw, h_b);

  // --- qkv projection ---
  k_gemm_p4<128, EPI_B16><<<dim3(32, 24), dim3(256), 0, stream>>>(
      h_b, wb_qkv, TBT, 3 * TD, TD, nullptr, nullptr, nullptr, qkv_b);

  // --- dd angles: [xh|xl|xh]·[wh|wh|wl]^T as one K=3072 GEMM ---
  k_gemm_p4<64, EPI_DD><<<dim3(64, 2), dim3(256), 0, stream>>>(
      xcat, wcat, TBT, 256, 3072, nullptr, dd_b, angles, nullptr);

  // --- cumsum + trig (3-phase, coalesced) ---
  k_csum1<<<dim3(2, 128), dim3(64), 0, stream>>>(angles, segsum);
  k_csum2<<<dim3(1), dim3(512), 0, stream>>>(segsum);
  k_csum3<<<dim3(2, 128), dim3(64), 0, stream>>>(angles, segsum, ddc, dds);

  k_qkv_post<<<dim3(32, 32), dim3(256), 0, stream>>>(
      qkv_b, ropec, ropes, ddc, dds, qnw, knw, qpb, kpb, qb, kb, vT);

  // --- attention ---
  k_attn<<<dim3(32, 32), dim3(256), 0, stream>>>(qb, kb, vT, y_b);

  // --- output proj + residual ---
  k_gemm_p4<128, EPI_RESID><<<dim3(32, 8), dim3(256), 0, stream>>>(
      y_b, wb_o, TBT, TD, TD, x_mix, nullptr, x2, nullptr);

  // --- MLP ---
  k_rmsnorm<<<dim3(TBT), dim3(256), 0, stream>>>(x2, mnw, h2_b);
  k_gemm_p4<128, EPI_B16><<<dim3(32, 43), dim3(256), 0, stream>>>(
      h2_b, wb_gu, TBT, 2 * TFFN, TD, nullptr, nullptr, nullptr, gu_b);
  k_swiglu<<<dim3((TBT * 344 + 255) / 256), dim3(256), 0, stream>>>(gu_b, hb);
  k_gemm_p4<128, EPI_RESID><<<dim3(32, 8), dim3(256), 0, stream>>>(
      hb, wb_down, TBT, TD, TFFNP, x2, nullptr, out, nullptr);
}

// Round 8
// 519.282 us; speedup vs baseline: 1.0617x; 1.0617x over previous
//
#include <hip/hip_runtime.h>

typedef unsigned short u16;
typedef __attribute__((ext_vector_type(8))) short short8;
typedef __attribute__((ext_vector_type(4))) short short4v;
typedef __attribute__((ext_vector_type(4))) float f32x4;
typedef __attribute__((ext_vector_type(4))) unsigned short u16x4;

static constexpr int TB   = 2;
static constexpr int TT   = 2048;
static constexpr int TD   = 1024;
static constexpr int TNH  = 16;
static constexpr int TDH  = 64;
static constexpr int TFFN = 2736;
static constexpr int TFFNP= 2752;   // K padded to multiple of 32
static constexpr int TBT  = TB * TT;

#define DEVI static __device__ __forceinline__

typedef __attribute__((address_space(1))) const unsigned int gas_t;
typedef __attribute__((address_space(3))) unsigned int las_t;
#define GLOAD16(src, dst) __builtin_amdgcn_global_load_lds((gas_t*)(src), (las_t*)(dst), 16, 0, 0)

DEVI u16 f2bf(float f) {
  union { float f; unsigned u; } v; v.f = f;
  unsigned r = v.u + 0x7FFFu + ((v.u >> 16) & 1u);
  return (u16)(r >> 16);
}
DEVI float bf2f(u16 u) {
  union { unsigned u; float f; } v; v.u = ((unsigned)u) << 16;
  return v.f;
}

// packed f32x2 -> bf16x2 (RNE), gfx950 v_cvt_pk_bf16_f32
DEVI unsigned cvtpk(float lo, float hi) {
  unsigned r;
  asm("v_cvt_pk_bf16_f32 %0, %1, %2" : "=v"(r) : "v"(lo), "v"(hi));
  return r;
}

#if __has_builtin(__builtin_amdgcn_mfma_f32_16x16x16bf16_1k)
#define MFMA16(a, b, c) __builtin_amdgcn_mfma_f32_16x16x16bf16_1k(a, b, c, 0, 0, 0)
#else
DEVI f32x4 mfma16_asm(short4v a, short4v b, f32x4 c) {
  asm("v_mfma_f32_16x16x16_bf16 %0, %1, %2, %0" : "+v"(c) : "v"(a), "v"(b));
  return c;
}
#define MFMA16(a, b, c) mfma16_asm(a, b, c)
#endif

// ------------------- merged converts (single launch) -----------------------
__global__ void k_cvt_all(const float* __restrict__ x,  const float* __restrict__ lw,
                          const float* __restrict__ wq, const float* __restrict__ wo,
                          const float* __restrict__ gw, const float* __restrict__ uw,
                          const float* __restrict__ dw, const float* __restrict__ ddw,
                          u16* __restrict__ xb,  u16* __restrict__ wbl,
                          u16* __restrict__ wbq, u16* __restrict__ wbo,
                          u16* __restrict__ wbgu, u16* __restrict__ wbd,
                          u16* __restrict__ wcat) {
  constexpr int U0 = TBT * TD / 4;        // x -> xb
  constexpr int U1 = TD * TD / 4;         // lerp_w
  constexpr int U2 = 3 * TD * TD / 4;     // w_qkv
  constexpr int U3 = TD * TD / 4;         // w_o
  constexpr int U4 = TFFN * TD / 4;       // gate
  constexpr int U5 = TFFN * TD / 4;       // up
  constexpr int U6 = TD * (TFFNP / 4);    // down (pad 2736->2752)
  constexpr int U7 = 256 * TD / 4;        // dd_w split3
  constexpr int P1 = U0, P2 = P1 + U1, P3 = P2 + U2, P4 = P3 + U3;
  constexpr int P5 = P4 + U4, P6 = P5 + U5, P7 = P6 + U6, PT = P7 + U7;
  int i = blockIdx.x * blockDim.x + threadIdx.x;
  int st = gridDim.x * blockDim.x;
  for (; i < PT; i += st) {
    if (i < P6) {
      const float* s; u16* d; int j;
      if (i < P1)      { s = x;  d = xb;  j = i; }
      else if (i < P2) { s = lw; d = wbl; j = i - P1; }
      else if (i < P3) { s = wq; d = wbq; j = i - P2; }
      else if (i < P4) { s = wo; d = wbo; j = i - P3; }
      else if (i < P5) { s = gw; d = wbgu; j = i - P4; }
      else             { s = uw; d = wbgu + (size_t)TFFN * TD; j = i - P5; }
      float4 v = ((const float4*)s)[j];
      u16x4 u;
      u.x = f2bf(v.x); u.y = f2bf(v.y); u.z = f2bf(v.z); u.w = f2bf(v.w);
      ((u16x4*)d)[j] = u;
    } else if (i < P7) {
      int j = i - P6;
      int c4 = j % (TFFNP / 4), r = j / (TFFNP / 4);
      u16x4 u;
      if (c4 < TFFN / 4) {
        const float* sp = dw + (size_t)r * TFFN + c4 * 4;
        u.x = f2bf(sp[0]); u.y = f2bf(sp[1]); u.z = f2bf(sp[2]); u.w = f2bf(sp[3]);
      } else { u.x = u.y = u.z = u.w = 0; }
      ((u16x4*)wbd)[(size_t)r * (TFFNP / 4) + c4] = u;
    } else {
      int j = i - P7;                       // 4 src elems of dd_w [256][1024]
      int c = (j & 255) * 4, r = j >> 8;
      float4 v = *(const float4*)(ddw + (size_t)r * 1024 + c);
      size_t base = (size_t)r * 3072 + c;
      #pragma unroll
      for (int e = 0; e < 4; e++) {
        float f = (e == 0) ? v.x : (e == 1) ? v.y : (e == 2) ? v.z : v.w;
        u16 h = f2bf(f);
        wcat[base + e] = h;
        wcat[base + 1024 + e] = h;
        wcat[base + 2048 + e] = f2bf(f - bf2f(h));
      }
    }
  }
}

// ----------------------------- rmsnorm ------------------------------------
__global__ __launch_bounds__(256) void k_rmsnorm(const float* __restrict__ x,
                                                 const float* __restrict__ w,
                                                 u16* __restrict__ o) {
  int row = blockIdx.x;
  float4 v = ((const float4*)(x + (size_t)row * TD))[threadIdx.x];
  float ss = v.x*v.x + v.y*v.y + v.z*v.z + v.w*v.w;
  #pragma unroll
  for (int m = 1; m < 64; m <<= 1) ss += __shfl_xor(ss, m);
  __shared__ float red[4];
  if ((threadIdx.x & 63) == 0) red[threadIdx.x >> 6] = ss;
  __syncthreads();
  float tot = red[0] + red[1] + red[2] + red[3];
  float sc = rsqrtf(tot * (1.0f / TD) + 1e-6f);
  float4 wv = ((const float4*)w)[threadIdx.x];
  u16x4 u;
  u.x = f2bf(v.x * sc * wv.x); u.y = f2bf(v.y * sc * wv.y);
  u.z = f2bf(v.z * sc * wv.z); u.w = f2bf(v.w * sc * wv.w);
  ((u16x4*)(o + (size_t)row * TD))[threadIdx.x] = u;
}

enum { EPI_LERP = 0, EPI_DD = 1, EPI_RESID = 2, EPI_B16 = 3 };

// -------- triple-buffered pipelined GEMM (race-free counted vmcnt) ---------
// C[M][N] = A[M][K]*B[N][K]^T. BMx128 tile, BK=32.
// BM=64/128: 4 waves (2x2), wave (BM/2)x64. BM=256: 8 waves (4x2), wave 64x64.
// THREE LDS K-step buffers. Per step: counted vmcnt (own stage(t) landed)
// BEFORE barrier => all waves' stage(t) landed at barrier => compute(t)
// race-free with no post-barrier wait; stages t+1/t+2 in flight across the
// barrier (T4). stage(t+2) post-barrier overwrites buf read at compute(t-1)
// => WAR-safe. LDS [row][32], 16B-unit ^= (row>>1)&3 on src AND read (R21).
template<int BM, int EPI>
__global__ __launch_bounds__(BM == 256 ? 512 : 256) void k_gemm_p4(
    const u16* __restrict__ A, const u16* __restrict__ B,
    int M, int N, int K,
    const float* __restrict__ aux0, const float* __restrict__ aux1,
    float* __restrict__ outF, u16* __restrict__ outB) {
  constexpr int MI = (BM == 256) ? 4 : BM / 32;   // acc rows per wave
  alignas(16) __shared__ u16 As[3][BM * 32];
  alignas(16) __shared__ u16 Bs[3][4096];
  const int lane = threadIdx.x & 63;
  const int w  = threadIdx.x >> 6;
  const int ln = lane & 15;
  const int g  = lane >> 4;
  const int swz = (ln >> 1) & 3;
  const int m0 = blockIdx.x * BM;
  const int n0 = blockIdx.y * 128;
  const int wm = (w >> 1) * ((BM == 256) ? 64 : BM / 2);
  const int wn = (w & 1) * 64;

  const f32x4 fz = {0.f, 0.f, 0.f, 0.f};
  f32x4 acc[MI][4];
  #pragma unroll
  for (int mi = 0; mi < MI; mi++)
    #pragma unroll
    for (int ni = 0; ni < 4; ni++) acc[mi][ni] = fz;

  const int rsub = lane >> 2;                       // row within 16-row unit
  const int csrc = (lane & 3) ^ ((lane >> 3) & 3);  // pre-swizzled k-unit
  auto stage = [&](int buf, int kt) {
    const int k0 = kt * 32 + csrc * 8;
    if constexpr (BM == 128) {
      #pragma unroll
      for (int i = 0; i < 2; i++) {
        const int u = w + i * 4;
        int ar = m0 + u * 16 + rsub;
        GLOAD16(A + (size_t)ar * K + k0, &As[buf][u * 512]);
        int br = n0 + u * 16 + rsub; if (br > N - 1) br = N - 1;
        GLOAD16(B + (size_t)br * K + k0, &Bs[buf][u * 512]);
      }
    } else if constexpr (BM == 256) {  // 8 waves: wave stages A-units {w,w+8}, B-unit w
      #pragma unroll
      for (int i = 0; i < 2; i++) {
        const int u = w + i * 8;
        int ar = m0 + u * 16 + rsub;
        GLOAD16(A + (size_t)ar * K + k0, &As[buf][u * 512]);
      }
      int br = n0 + w * 16 + rsub; if (br > N - 1) br = N - 1;
      GLOAD16(B + (size_t)br * K + k0, &Bs[buf][w * 512]);
    } else {                     // BM == 64
      int ar = m0 + w * 16 + rsub;
      GLOAD16(A + (size_t)ar * K + k0, &As[buf][w * 512]);
      #pragma unroll
      for (int i = 0; i < 2; i++) {
        const int u = w + i * 4;
        int br = n0 + u * 16 + rsub; if (br > N - 1) br = N - 1;
        GLOAD16(B + (size_t)br * K + k0, &Bs[buf][u * 512]);
      }
    }
  };

  auto compute = [&](int cur) {
    short8 af[MI], bfr[4];
    #pragma unroll
    for (int mi = 0; mi < MI; mi++)
      af[mi] = *(const short8*)&As[cur][(wm + mi * 16 + ln) * 32 + ((g ^ swz) << 3)];
    #pragma unroll
    for (int ni = 0; ni < 4; ni++)
      bfr[ni] = *(const short8*)&Bs[cur][(wn + ni * 16 + ln) * 32 + ((g ^ swz) << 3)];
    __builtin_amdgcn_s_setprio(1);
    #pragma unroll
    for (int mi = 0; mi < MI; mi++)
      #pragma unroll
      for (int ni = 0; ni < 4; ni++)
        acc[mi][ni] = __builtin_amdgcn_mfma_f32_16x16x32_bf16(af[mi], bfr[ni], acc[mi][ni], 0, 0, 0);
    __builtin_amdgcn_s_setprio(0);
  };

  const int nt = K / 32;
  stage(0, 0);
  stage(1, 1);
  int cur = 0, nx2 = 2;                 // t%3, (t+2)%3
  for (int t = 0; t < nt; ++t) {
    if (t + 1 < nt) {
      if constexpr (BM == 128) asm volatile("s_waitcnt vmcnt(4)" ::: "memory");
      else                     asm volatile("s_waitcnt vmcnt(3)" ::: "memory");
    } else {
      asm volatile("s_waitcnt vmcnt(0)" ::: "memory");
    }
    __builtin_amdgcn_s_barrier();
    asm volatile("" ::: "memory");
    if (t + 2 < nt) stage(nx2, t + 2);
    compute(cur);
    cur = (cur == 2) ? 0 : cur + 1;
    nx2 = (nx2 == 2) ? 0 : nx2 + 1;
  }

  // epilogue: C layout col=lane&15, row=(lane>>4)*4+reg
  #pragma unroll
  for (int mi = 0; mi < MI; mi++) {
    #pragma unroll
    for (int ni = 0; ni < 4; ni++) {
      int col = n0 + wn + ni * 16 + ln;
      #pragma unroll
      for (int r = 0; r < 4; r++) {
        int row = m0 + wm + mi * 16 + g * 4 + r;
        if (row >= M || col >= N) continue;
        float c = acc[mi][ni][r];
        size_t o = (size_t)row * N + col;
        if constexpr (EPI == EPI_LERP) {
          float gg = 1.0f / (1.0f + __expf(-(c + aux1[col])));
          float xv = aux0[o];
          float xp = (row & (TT - 1)) ? aux0[o - N] : 0.0f;
          float res = xv + gg * (xp - xv);
          outF[o] = res;
          u16 hi = f2bf(res);
          size_t xc = (size_t)row * 3072 + col;
          outB[xc] = hi;
          outB[xc + 2048] = hi;
          outB[xc + 1024] = f2bf(res - bf2f(hi));
        } else if constexpr (EPI == EPI_DD) {
          outF[o] = c + aux1[col];
        } else if constexpr (EPI == EPI_RESID) {
          outF[o] = aux0[o] + c;
        } else {
          outB[o] = f2bf(c);
        }
      }
    }
  }
}

// ------------------------- cumsum (3-phase) --------------------------------
__global__ __launch_bounds__(64) void k_csum1(const float* __restrict__ ang,
                                              float* __restrict__ seg) {
  int b = blockIdx.x, sg = blockIdx.y, q = threadIdx.x;
  const float4* p = (const float4*)(ang + ((size_t)(b * TT + sg * 16)) * 256) + q;
  float4 a = {0.f, 0.f, 0.f, 0.f};
  #pragma unroll 4
  for (int i = 0; i < 16; i++) {
    float4 v = p[(size_t)i * 64];
    a.x += v.x; a.y += v.y; a.z += v.z; a.w += v.w;
  }
  ((float4*)(seg + ((size_t)(b * 128 + sg)) * 256))[q] = a;
}

// batched: 16 independent loads per round, then sequential prefix writeback
__global__ __launch_bounds__(512) void k_csum2(float* __restrict__ seg) {
  int b = threadIdx.x >> 8, col = threadIdx.x & 255;
  float run = 0.f;
  for (int s0 = 0; s0 < 128; s0 += 16) {
    float v[16];
    #pragma unroll
    for (int i = 0; i < 16; i++)
      v[i] = seg[((size_t)(b * 128 + s0 + i)) * 256 + col];
    #pragma unroll
    for (int i = 0; i < 16; i++) {
      float t = v[i];
      seg[((size_t)(b * 128 + s0 + i)) * 256 + col] = run;
      run += t;
    }
  }
}

__global__ __launch_bounds__(64) void k_csum3(const float* __restrict__ ang,
                                              const float* __restrict__ seg,
                                              float* __restrict__ dc,
                                              float* __restrict__ ds) {
  int b = blockIdx.x, sg = blockIdx.y, q = threadIdx.x;
  size_t rowbase = ((size_t)(b * TT + sg * 16)) * 256;
  const float4* p = (const float4*)(ang + rowbase) + q;
  float4 a = ((const float4*)(seg + ((size_t)(b * 128 + sg)) * 256))[q];
  for (int i = 0; i < 16; i++) {
    float4 v = p[(size_t)i * 64];
    a.x += v.x; a.y += v.y; a.z += v.z; a.w += v.w;
    float4 c, s;
    c.x = cosf(a.x); s.x = sinf(a.x);
    c.y = cosf(a.y); s.y = sinf(a.y);
    c.z = cosf(a.z); s.z = sinf(a.z);
    c.w = cosf(a.w); s.w = sinf(a.w);
    ((float4*)(dc + rowbase))[(size_t)i * 64 + q] = c;
    ((float4*)(ds + rowbase))[(size_t)i * 64 + q] = s;
  }
}

// ----------------- qkv post: head RMS + hybrid rope + V^T ------------------
__global__ __launch_bounds__(256) void k_qkv_post(
    const u16* __restrict__ qkv, const float* __restrict__ rc, const float* __restrict__ rs,
    const float* __restrict__ ddc, const float* __restrict__ dds,
    const float* __restrict__ qnw, const float* __restrict__ knw,
    const float* __restrict__ qpb, const float* __restrict__ kpb,
    u16* __restrict__ qb, u16* __restrict__ kb, u16* __restrict__ vT) {
  __shared__ u16 vt[64][72];
  const int lane = threadIdx.x & 63;
  const int w = threadIdx.x >> 6;
  const int bh = blockIdx.x, b = bh >> 4, h = bh & 15;
  const int t0 = blockIdx.y * 64;
  const float qsc = 0.125f * 1.44269504f;   // 1/sqrt(DH) * log2e
  const float qw = qnw[lane] * qpb[lane];
  const float kw = knw[lane] * kpb[lane];
  const float sgn = (lane & 16) ? 1.0f : -1.0f;
  #pragma unroll 4
  for (int it = 0; it < 16; ++it) {
    int tl = w * 16 + it;
    int t = t0 + tl;
    size_t base = ((size_t)(b * TT + t)) * 3072 + h * 64 + lane;
    float q = bf2f(qkv[base]);
    float k = bf2f(qkv[base + 1024]);
    float v = bf2f(qkv[base + 2048]);
    float sq = q * q, sk = k * k;
    #pragma unroll
    for (int m = 1; m < 64; m <<= 1) { sq += __shfl_xor(sq, m); sk += __shfl_xor(sk, m); }
    q *= rsqrtf(sq * (1.0f / TDH) + 1e-6f) * qw;
    k *= rsqrtf(sk * (1.0f / TDH) + 1e-6f) * kw;
    float c, s;
    if (lane < 32) {
      c = rc[t * 32 + (lane & 15)];
      s = rs[t * 32 + (lane & 15)];
    } else {
      size_t ti = ((size_t)(b * TT + t)) * 256 + h * 16 + (lane & 15);
      c = ddc[ti];
      s = dds[ti];
    }
    float oq = __shfl_xor(q, 16);
    float ok = __shfl_xor(k, 16);
    float qr = (q * c + sgn * oq * s) * qsc;
    float kr = k * c + sgn * ok * s;
    size_t o = ((size_t)(bh * TT + t)) * 64 + lane;
    qb[o] = f2bf(qr);
    kb[o] = f2bf(kr);
    vt[lane][tl] = f2bf(v);
  }
  __syncthreads();
  int row = threadIdx.x >> 2, sg = threadIdx.x & 3;
  short8 v0 = *(const short8*)&vt[row][sg * 16];
  short8 v1 = *(const short8*)&vt[row][sg * 16 + 8];
  size_t o = ((size_t)(bh * 64 + row)) * TT + t0 + sg * 16;
  *(short8*)(vT + o) = v0;
  *(short8*)(vT + o + 8) = v1;
}

// --------------------------- flash attention -------------------------------
__global__ __launch_bounds__(256) void k_attn(
    const u16* __restrict__ qb, const u16* __restrict__ kb,
    const u16* __restrict__ vT, u16* __restrict__ y) {
  __shared__ u16 smem[16384];         // Ks[2][4096] | Vs[2][4096]
  u16* Ks = smem;
  u16* Vs = smem + 8192;
  const int lane = threadIdx.x & 63;
  const int w = threadIdx.x >> 6;
  const int ln = lane & 15;
  const int g = lane >> 4;
  const int gh = g >> 1, gl = g & 1;
  const int bh = blockIdx.x;
  const int b = bh >> 4;
  const int by = 31 - (int)blockIdx.y;     // LPT: longest first
  const int qt0 = by * 64 + w * 16;
  const u16* Q  = qb + (size_t)bh * TT * TDH;
  const u16* Kp = kb + (size_t)bh * TT * TDH;
  const u16* Vp = vT + (size_t)bh * TDH * TT;
  short8 qa0 = *(const short8*)(Q + (size_t)(qt0 + ln) * TDH + g * 8);
  short8 qa1 = *(const short8*)(Q + (size_t)(qt0 + ln) * TDH + 32 + g * 8);
  const f32x4 fz = {0.f, 0.f, 0.f, 0.f};
  f32x4 O[4];
  #pragma unroll
  for (int r = 0; r < 4; r++) O[r] = fz;
  float m = -1e30f, l = 0.0f;
  const int qlim = qt0 + ln;

  auto stage = [&](int buf, int j0) {
    #pragma unroll
    for (int i = 0; i < 2; i++) {
      int r = w * 16 + i * 8 + (lane >> 3);
      int c = (lane & 7) ^ (r & 7);
      GLOAD16(Kp + (size_t)(j0 + r) * TDH + c * 8, &Ks[buf * 4096 + w * 1024 + i * 512]);
      GLOAD16(Vp + (size_t)r * TT + j0 + c * 8, &Vs[buf * 4096 + w * 1024 + i * 512]);
    }
  };

  const int nt = by + 1;
  stage(0, 0);
  __syncthreads();
  for (int jt = 0; jt < nt; ++jt) {
    const int cur = jt & 1;
    if (jt + 1 < nt) stage(cur ^ 1, (jt + 1) * 64);
    const int j0 = jt * 64;
    f32x4 sc[4];
    __builtin_amdgcn_s_setprio(1);
    #pragma unroll
    for (int c4 = 0; c4 < 4; c4++) {
      const u16* kr = Ks + cur * 4096 + (c4 * 16 + ln) * 64;
      short8 k0 = *(const short8*)(kr + ((g ^ (ln & 7)) * 8));
      short8 k1 = *(const short8*)(kr + (((g + 4) ^ (ln & 7)) * 8));
      f32x4 z = fz;
      z = __builtin_amdgcn_mfma_f32_16x16x32_bf16(k0, qa0, z, 0, 0, 0);
      z = __builtin_amdgcn_mfma_f32_16x16x32_bf16(k1, qa1, z, 0, 0, 0);
      sc[c4] = z;
    }
    __builtin_amdgcn_s_setprio(0);
    if (jt == nt - 1) {              // diagonal: mask j > q
      #pragma unroll
      for (int c4 = 0; c4 < 4; c4++)
        #pragma unroll
        for (int r = 0; r < 4; r++)
          if (j0 + c4 * 16 + g * 4 + r > qlim) sc[c4][r] = -1e30f;
    }
    float pm = sc[0][0];
    #pragma unroll
    for (int c4 = 0; c4 < 4; c4++)
      #pragma unroll
      for (int r = 0; r < 4; r++) pm = fmaxf(pm, sc[c4][r]);
    pm = fmaxf(pm, __shfl_xor(pm, 16));
    pm = fmaxf(pm, __shfl_xor(pm, 32));
    bool grow = pm > m + 10.0f;
    if (__ballot(grow) != 0ull) {
      float mn = fmaxf(m, pm);
      float corr = exp2f(m - mn);
      #pragma unroll
      for (int dc = 0; dc < 4; dc++)
        #pragma unroll
        for (int r = 0; r < 4; r++) O[dc][r] *= corr;
      l *= corr;
      m = mn;
    }
    float rs_ = 0.0f;
    #pragma unroll
    for (int c4 = 0; c4 < 4; c4++)
      #pragma unroll
      for (int r = 0; r < 4; r++) {
        float pv = exp2f(sc[c4][r] - m);
        rs_ += pv;
        sc[c4][r] = pv;
      }
    rs_ += __shfl_xor(rs_, 16);
    rs_ += __shfl_xor(rs_, 32);
    l += rs_;
    short4v p4[4];
    #pragma unroll
    for (int c4 = 0; c4 < 4; c4++) {
      union { unsigned u[2]; short4v s; } pu;
      pu.u[0] = cvtpk(sc[c4][0], sc[c4][1]);
      pu.u[1] = cvtpk(sc[c4][2], sc[c4][3]);
      p4[c4] = pu.s;
    }
    __builtin_amdgcn_s_setprio(1);
    #pragma unroll
    for (int dc = 0; dc < 4; dc++) {
      const int vrow = dc * 16 + ln;
      const u16* vbase = Vs + cur * 4096 + vrow * 64;
      #pragma unroll
      for (int c4 = 0; c4 < 4; c4++) {
        int chunk = (2 * c4 + gh) ^ (ln & 7);
        short4v va = *(const short4v*)(vbase + chunk * 8 + gl * 4);
        O[dc] = MFMA16(va, p4[c4], O[dc]);
      }
    }
    __builtin_amdgcn_s_setprio(0);
    __syncthreads();
  }
  // epilogue: transpose O^T via LDS for coalesced y writes
  u16* ot = smem + w * 1152;           // 16 rows x 72
  float inv = 1.0f / l;
  #pragma unroll
  for (int dc = 0; dc < 4; dc++)
    #pragma unroll
    for (int r = 0; r < 4; r += 2) {
      unsigned pk = cvtpk(O[dc][r] * inv, O[dc][r + 1] * inv);
      *(unsigned*)(ot + ln * 72 + dc * 16 + g * 4 + r) = pk;
    }
  __syncthreads();
  int row = (threadIdx.x & 63) >> 2, sg = threadIdx.x & 3;
  u16* os = smem + w * 1152;
  short8 v0 = *(const short8*)(os + row * 72 + sg * 16);
  short8 v1 = *(const short8*)(os + row * 72 + sg * 16 + 8);
  size_t o = ((size_t)(b * TT + qt0 + row)) * TD + (bh & 15) * TDH + sg * 16;
  *(short8*)(y + o) = v0;
  *(short8*)(y + o + 8) = v1;
}

// ------------------------------ swiglu -------------------------------------
__global__ void k_swiglu(const u16* __restrict__ gu, u16* __restrict__ hb) {
  int i = blockIdx.x * blockDim.x + threadIdx.x;
  int n = TBT * 344;
  if (i >= n) return;
  int c8 = i % 344, r = i / 344;
  short8 o;
  if (c8 < 342) {
    short8 gv = *(const short8*)(gu + (size_t)r * 5472 + c8 * 8);
    short8 uv = *(const short8*)(gu + (size_t)r * 5472 + 2736 + c8 * 8);
    #pragma unroll
    for (int j = 0; j < 8; j++) {
      float gf = bf2f((u16)gv[j]);
      float uf = bf2f((u16)uv[j]);
      float sg = gf / (1.0f + __expf(-gf));
      o[j] = (short)f2bf(sg * uf);
    }
  } else {
    #pragma unroll
    for (int j = 0; j < 8; j++) o[j] = 0;
  }
  *(short8*)(hb + (size_t)r * TFFNP + c8 * 8) = o;
}

// ----------------------------- launcher ------------------------------------
extern "C" void kernel_launch(void* const* d_in, const int* in_sizes, int n_in,
                              void* d_out, int out_size, void* d_ws, size_t ws_size,
                              hipStream_t stream) {
  const float* x      = (const float*)d_in[0];
  const float* ropec  = (const float*)d_in[1];
  const float* ropes  = (const float*)d_in[2];
  const float* lerp_w = (const float*)d_in[3];
  const float* lerp_b = (const float*)d_in[4];
  const float* anw    = (const float*)d_in[5];
  const float* w_qkv  = (const float*)d_in[6];
  const float* qnw    = (const float*)d_in[7];
  const float* knw    = (const float*)d_in[8];
  const float* qpb    = (const float*)d_in[9];
  const float* kpb    = (const float*)d_in[10];
  const float* dd_w   = (const float*)d_in[11];
  const float* dd_b   = (const float*)d_in[12];
  const float* w_o    = (const float*)d_in[13];
  const float* mnw    = (const float*)d_in[14];
  const float* gate_w = (const float*)d_in[15];
  const float* up_w   = (const float*)d_in[16];
  const float* down_w = (const float*)d_in[17];
  float* out = (float*)d_out;
  (void)in_sizes; (void)n_in; (void)out_size; (void)ws_size;

  char* ws = (char*)d_ws;
  size_t off = 0;
  auto alloc = [&](size_t bytes) -> char* {
    char* p = ws + off;
    off += (bytes + 255) & ~(size_t)255;
    return p;
  };

  // region A..E (dead before gate/up): aliased by gu_b (44.83MB <= 50.34MB)
  char* segA = ws;
  u16* xb      = (u16*)alloc((size_t)TBT * TD * 2);        // 8.39
  u16* wb_lerp = (u16*)alloc((size_t)TD * TD * 2);         // 2.10
  u16* wb_qkv  = (u16*)alloc((size_t)3 * TD * TD * 2);     // 6.29
  u16* h_b     = (u16*)alloc((size_t)TBT * TD * 2);        // 8.39
  u16* xcat    = (u16*)alloc((size_t)TBT * 3072 * 2);      // 25.17
  u16* gu_b    = (u16*)segA;

  // region F (dead before swiglu): aliased by hb (22.53 <= 25.17)
  char* segF = ws + off;
  u16* qkv_b   = (u16*)alloc((size_t)TBT * 3 * TD * 2);    // 25.17
  u16* hb      = (u16*)segF;

  // persistent
  u16* wcat    = (u16*)alloc((size_t)256 * 3072 * 2);
  u16* wb_o    = (u16*)alloc((size_t)TD * TD * 2);
  u16* wb_gu   = (u16*)alloc((size_t)2 * TFFN * TD * 2);
  u16* wb_down = (u16*)alloc((size_t)TD * TFFNP * 2);
  float* x_mix = (float*)alloc((size_t)TBT * TD * 4);
  float* angles= (float*)alloc((size_t)TBT * 256 * 4);
  float* ddc   = (float*)alloc((size_t)TBT * 256 * 4);
  float* dds   = (float*)alloc((size_t)TBT * 256 * 4);
  float* segsum= (float*)alloc((size_t)2 * 128 * 256 * 4);
  u16* qb  = (u16*)alloc((size_t)TBT * TD * 2);
  u16* kb  = (u16*)alloc((size_t)TBT * TD * 2);
  u16* vT  = (u16*)alloc((size_t)TBT * TD * 2);
  u16* y_b = (u16*)alloc((size_t)TBT * TD * 2);
  float* x2  = (float*)alloc((size_t)TBT * TD * 4);
  u16* h2_b  = (u16*)alloc((size_t)TBT * TD * 2);

  // --- all dtype converts in one launch ---
  k_cvt_all<<<dim3(2048), dim3(256), 0, stream>>>(
      x, lerp_w, w_qkv, w_o, gate_w, up_w, down_w, dd_w,
      xb, wb_lerp, wb_qkv, wb_o, wb_gu, wb_down, wcat);

  // --- lerp gate (x = (1-g)x + g x_prev), also emits xcat = [hi|lo|hi] ---
  k_gemm_p4<64, EPI_LERP><<<dim3(64, 8), dim3(256), 0, stream>>>(
      xb, wb_lerp, TBT, TD, TD, x, lerp_b, x_mix, xcat);

  k_rmsnorm<<<dim3(TBT), dim3(256), 0, stream>>>(x_mix, anw, h_b);

  // --- qkv projection ---
  k_gemm_p4<128, EPI_B16><<<dim3(32, 24), dim3(256), 0, stream>>>(
      h_b, wb_qkv, TBT, 3 * TD, TD, nullptr, nullptr, nullptr, qkv_b);

  // --- dd angles: [xh|xl|xh]·[wh|wh|wl]^T as one K=3072 GEMM ---
  k_gemm_p4<64, EPI_DD><<<dim3(64, 2), dim3(256), 0, stream>>>(
      xcat, wcat, TBT, 256, 3072, nullptr, dd_b, angles, nullptr);

  // --- cumsum + trig (3-phase, coalesced) ---
  k_csum1<<<dim3(2, 128), dim3(64), 0, stream>>>(angles, segsum);
  k_csum2<<<dim3(1), dim3(512), 0, stream>>>(segsum);
  k_csum3<<<dim3(2, 128), dim3(64), 0, stream>>>(angles, segsum, ddc, dds);

  k_qkv_post<<<dim3(32, 32), dim3(256), 0, stream>>>(
      qkv_b, ropec, ropes, ddc, dds, qnw, knw, qpb, kpb, qb, kb, vT);

  // --- attention ---
  k_attn<<<dim3(32, 32), dim3(256), 0, stream>>>(qb, kb, vT, y_b);

  // --- output proj + residual ---
  k_gemm_p4<64, EPI_RESID><<<dim3(64, 8), dim3(256), 0, stream>>>(
      y_b, wb_o, TBT, TD, TD, x_mix, nullptr, x2, nullptr);

  // --- MLP ---
  k_rmsnorm<<<dim3(TBT), dim3(256), 0, stream>>>(x2, mnw, h2_b);
  k_gemm_p4<256, EPI_B16><<<dim3(16, 43), dim3(512), 0, stream>>>(
      h2_b, wb_gu, TBT, 2 * TFFN, TD, nullptr, nullptr, nullptr, gu_b);
  k_swiglu<<<dim3((TBT * 344 + 255) / 256), dim3(256), 0, stream>>>(gu_b, hb);
  k_gemm_p4<64, EPI_RESID><<<dim3(64, 8), dim3(256), 0, stream>>>(
      hb, wb_down, TBT, TD, TFFNP, x2, nullptr, out, nullptr);
}